// Round 6
// baseline (340.337 us; speedup 1.0000x reference)
//
#include <hip/hip_runtime.h>

#define LOG2E 1.4426950408889634f
#define LN2   0.6931471805599453f

__device__ __forceinline__ float x2(float x)  { return __builtin_amdgcn_exp2f(x); }
__device__ __forceinline__ float lg2(float x) { return __builtin_amdgcn_logf(x); }

// Phase 1: per-(b,t) softmax normalizer + gather token PROBABILITIES (linear
// domain). Labels -> em[row*128 + j]; blank replicated 64x -> embr[row*64+lane]
// (per-lane varying addresses so the DP kernel never issues a wave-uniform
// load -> no SMEM scalarization -> no lgkmcnt(0) serialization vs bpermute).
__global__ __launch_bounds__(256) void emit_kernel(const float* __restrict__ pred,
                                                   const int* __restrict__ target,
                                                   float* __restrict__ em,
                                                   float* __restrict__ embr,
                                                   int T, int V, int L) {
    int wave = threadIdx.x >> 6;
    int lane = threadIdx.x & 63;
    int row = blockIdx.x * 4 + wave;            // row = b*T + t
    const float* rowp = pred + (size_t)row * V;
    int nq = V >> 2;                            // 250 float4s
    float4 v0, v1, v2, v3;
    const float4 fill = make_float4(-3.0e38f, -3.0e38f, -3.0e38f, -3.0e38f);
    v0 = (lane       < nq) ? ((const float4*)rowp)[lane]       : fill;
    v1 = (lane + 64  < nq) ? ((const float4*)rowp)[lane + 64]  : fill;
    v2 = (lane + 128 < nq) ? ((const float4*)rowp)[lane + 128] : fill;
    v3 = (lane + 192 < nq) ? ((const float4*)rowp)[lane + 192] : fill;
    float lm = fmaxf(fmaxf(fmaxf(v0.x, v0.y), fmaxf(v0.z, v0.w)),
               fmaxf(fmaxf(fmaxf(v1.x, v1.y), fmaxf(v1.z, v1.w)),
               fmaxf(fmaxf(fmaxf(v2.x, v2.y), fmaxf(v2.z, v2.w)),
                     fmaxf(fmaxf(v3.x, v3.y), fmaxf(v3.z, v3.w)))));
    #pragma unroll
    for (int off = 32; off > 0; off >>= 1) lm = fmaxf(lm, __shfl_xor(lm, off));
    float mm = lm * LOG2E;                      // row max in log2 units
    float ls = 0.f;
    if (lane < nq)
        ls += x2(fmaf(v0.x, LOG2E, -mm)) + x2(fmaf(v0.y, LOG2E, -mm))
            + x2(fmaf(v0.z, LOG2E, -mm)) + x2(fmaf(v0.w, LOG2E, -mm));
    if (lane + 64 < nq)
        ls += x2(fmaf(v1.x, LOG2E, -mm)) + x2(fmaf(v1.y, LOG2E, -mm))
            + x2(fmaf(v1.z, LOG2E, -mm)) + x2(fmaf(v1.w, LOG2E, -mm));
    if (lane + 128 < nq)
        ls += x2(fmaf(v2.x, LOG2E, -mm)) + x2(fmaf(v2.y, LOG2E, -mm))
            + x2(fmaf(v2.z, LOG2E, -mm)) + x2(fmaf(v2.w, LOG2E, -mm));
    if (lane + 192 < nq)
        ls += x2(fmaf(v3.x, LOG2E, -mm)) + x2(fmaf(v3.y, LOG2E, -mm))
            + x2(fmaf(v3.z, LOG2E, -mm)) + x2(fmaf(v3.w, LOG2E, -mm));
    #pragma unroll
    for (int off = 32; off > 0; off >>= 1) ls += __shfl_xor(ls, off);
    float n2 = mm + lg2(ls);                    // log2 normalizer

    int b = row / T;
    const int* tg = target + b * L;
    float* emrow = em + (size_t)row * 128;
    for (int j = lane; j < L; j += 64) {
        int tok = tg[j];
        emrow[j] = x2(fmaf(rowp[tok], LOG2E, -n2));   // linear probability
    }
    float blank_logit = __shfl(v0.x, 0);        // pred[row][0] (token 0)
    embr[(size_t)row * 64 + lane] = x2(fmaf(blank_logit, LOG2E, -n2));
}

// One linear-domain DP step. Named prefetch regs (no arrays -> no LDS
// promotion). stored = true * 2^K per lane; left-neighbor value re-framed by
// ldexp(K-Kp). The neighbor pre-selects what THIS lane needs (skipAn trick)
// so only 2 bpermutes/step. Zero transcendentals, zero uniform loads.
#define DP_STEP(EL, EC)                                                   \
  do {                                                                    \
    float ex0 = EL.x, ex1 = EL.y, eb = EC;                                \
    int tp = t + 8; if (tp > Tm1) tp = Tm1;                               \
    EL = *(const float2*)(eLb + (size_t)tp * 128 + 2 * lane);             \
    EC = eRb[(size_t)tp * 64 + lane];                                     \
    float r  = a3 + a2;                                                   \
    float q  = a1 + a0;                                                   \
    float w  = skipAn ? r : a3;     /* value my RIGHT neighbor needs */   \
    float ur = __shfl_up(w, 1);                                           \
    int   Kp = __shfl_up(K, 1);                                           \
    K = act ? K : Kp;                                                     \
    float uc = ldexpf(ur, K - Kp);                                        \
    float sb = s1 + star_st;                                              \
    if (lane == 0) uc = sb;                                               \
    S += slot0 ? q : r;                                                   \
    a2 = ex1 * (a2 + (skipB ? q : a1));                                   \
    a0 = ex0 * (a0 + uc);                                                 \
    a1 = eb * q;                                                          \
    a3 = eb * r;                                                          \
    s1 = eb * sb;                                                         \
    act = act || (uc > 0.0f);                                             \
    ++t;                                                                  \
  } while (0)

// Per-lane renorm: rescale stored values so lane max ~ 1, fold into K.
// Inactive lanes (m4==0) keep K (adoption handles them). S shares the frame.
#define RENORM                                                            \
  do {                                                                    \
    float m4 = fmaxf(fmaxf(a0, a1), fmaxf(a2, a3));                       \
    int e = (int)((__float_as_uint(m4) >> 23) & 255u) - 127;              \
    int d = act ? -e : 0;                                                 \
    float sc = ldexpf(1.0f, d);                                           \
    a0 *= sc; a1 *= sc; a2 *= sc; a3 *= sc; s1 *= sc; S *= sc;            \
    K += d;                                                               \
    star_st = ldexpf(sbase, K);                                           \
  } while (0)

// Phase 2: barrier-free single-wave W-CTC DP, LINEAR domain with per-lane
// block exponents. Lane i owns states s=4i+2..4i+5; star (true value 1) and
// s=1 live on lane 0. total = sum over t of (alpha_t[ll] + alpha_t[lb]).
__global__ __launch_bounds__(64) void dp_kernel(const float* __restrict__ em,
                                                const float* __restrict__ embr,
                                                const int* __restrict__ target,
                                                const int* __restrict__ tlen,
                                                float* __restrict__ nll,
                                                int T, int L) {
    int b = blockIdx.x;
    int lane = threadIdx.x;
    const float* eLb = em + (size_t)b * T * 128;
    const float* eRb = embr + (size_t)b * T * 64;
    const int* tg = target + b * L;
    int Tm1 = T - 1;

    int t0 = tg[2 * lane];
    int t1 = tg[2 * lane + 1];
    int tprev = __shfl_up(t1, 1);                // garbage on lane 0 (unused)
    bool skipA = (lane == 0) || (t0 != tprev);
    // my right neighbor's skipA (what to pre-select for them); lane63 dontcare
    bool skipAn = (__shfl_down((int)skipA, 1) != 0);

    bool skipB = (t1 != t0);

    int tl = tlen[b];
    int ll = 2 * tl;
    int lane_e = (ll - 2) >> 2;
    bool slot0 = ((ll - 2) & 3) == 0;            // ll,lb in (a0,a1) vs (a2,a3)

    // t=0 init (linear): star=1 (lane0), s=1 -> blank prob, s=2 -> label0 prob
    float2 e0 = *(const float2*)(eLb + 2 * lane);
    float a0 = (lane == 0) ? e0.x : 0.f;
    float a1 = 0.f, a2 = 0.f, a3 = 0.f;
    float s1 = (lane == 0) ? eRb[lane] : 0.f;
    float sbase = (lane == 0) ? 1.0f : 0.0f;
    int   K = 0;
    float star_st = sbase;                       // star stored = 1 * 2^K (lane 0)
    bool  act = (lane == 0);
    float S = 0.f;                               // running sum of alpha_t[ll]+[lb]

    // 8 named prefetch register sets (NOT arrays — avoids alloca->LDS)
    float2 L0, L1, L2, L3, L4, L5, L6, L7;
    float  C0, C1, C2, C3, C4, C5, C6, C7;
    #define PRELOAD(KK)                                                    \
      { int tp = 1 + KK; if (tp > Tm1) tp = Tm1;                           \
        L##KK = *(const float2*)(eLb + (size_t)tp * 128 + 2 * lane);       \
        C##KK = eRb[(size_t)tp * 64 + lane]; }
    PRELOAD(0) PRELOAD(1) PRELOAD(2) PRELOAD(3)
    PRELOAD(4) PRELOAD(5) PRELOAD(6) PRELOAD(7)
    #undef PRELOAD

    int t = 1;
    int ng = (T - 1) >> 3;                       // full groups of 8 steps
    for (int g = 0; g < ng; ++g) {
        DP_STEP(L0, C0); DP_STEP(L1, C1); DP_STEP(L2, C2); DP_STEP(L3, C3);
        RENORM;
        DP_STEP(L4, C4); DP_STEP(L5, C5); DP_STEP(L6, C6); DP_STEP(L7, C7);
        RENORM;
    }
    // tail (< 8 steps): registers already hold rows t..T-1 (clamped preloads)
    if (t < T) DP_STEP(L0, C0);
    if (t < T) DP_STEP(L1, C1);
    if (t < T) DP_STEP(L2, C2);
    if (t < T) DP_STEP(L3, C3);
    if (t < T) DP_STEP(L4, C4);
    if (t < T) DP_STEP(L5, C5);
    if (t < T) DP_STEP(L6, C6);

    {   // final alpha_{T-1}[ll],[lb] contribution
        float q = a1 + a0;
        float r = a3 + a2;
        S += slot0 ? q : r;
    }
    float Sv = __shfl(S, lane_e);
    int   Kv = __shfl(K, lane_e);
    if (lane == 0) nll[b] = -((lg2(Sv) - (float)Kv) * LN2);   // back to nats
}

// Phase 3: out = mean_b( nll[b] / tlen[b] )
__global__ __launch_bounds__(64) void fin_kernel(const float* __restrict__ nll,
                                                 const int* __restrict__ tlen,
                                                 float* __restrict__ out, int B) {
    int tid = threadIdx.x;
    float v = (tid < B) ? nll[tid] / (float)tlen[tid] : 0.f;
    #pragma unroll
    for (int off = 32; off > 0; off >>= 1) v += __shfl_xor(v, off);
    if (tid == 0) out[0] = v / (float)B;
}

extern "C" void kernel_launch(void* const* d_in, const int* in_sizes, int n_in,
                              void* d_out, int out_size, void* d_ws, size_t ws_size,
                              hipStream_t stream) {
    const float* pred   = (const float*)d_in[0];
    const int*   target = (const int*)d_in[1];
    const int*   tlen   = (const int*)d_in[2];
    int B = in_sizes[2];
    int L = in_sizes[1] / B;            // 128
    int V = 1000;                       // fixed by the problem
    int T = in_sizes[0] / (B * V);      // 1024

    float* ws   = (float*)d_ws;
    float* nll  = ws;                   // 64 floats
    float* embr = ws + 64;              // B*T*64 floats (~8.4 MB, blank x64)
    float* em   = embr + (size_t)B * T * 64;  // B*T*128 floats (~16.8 MB)

    emit_kernel<<<(B * T) / 4, 256, 0, stream>>>(pred, target, em, embr, T, V, L);
    dp_kernel<<<B, 64, 0, stream>>>(em, embr, target, tlen, nll, T, L);
    fin_kernel<<<1, 64, 0, stream>>>(nll, tlen, (float*)d_out, B);
}

// Round 7
// 317.426 us; speedup vs baseline: 1.0722x; 1.0722x over previous
//
#include <hip/hip_runtime.h>

#define LOG2E 1.4426950408889634f
#define LN2   0.6931471805599453f

__device__ __forceinline__ float x2(float x)  { return __builtin_amdgcn_exp2f(x); }
__device__ __forceinline__ float lg2(float x) { return __builtin_amdgcn_logf(x); }

// Phase 1: per-(b,t) softmax normalizer + gather token PROBABILITIES into
// PAIR-MAJOR layouts (2 timesteps per load in the DP):
//   emA[(b*T/2+p)*256 + i*4 + par*2 + {0,1}] = labels 2i,2i+1 at t=2p+par
//   emB[(b*T/2+p)*128 + lane*2 + par]        = blank at t=2p+par
// One wave per row, 4 waves per block, no LDS, no barriers.
__global__ __launch_bounds__(256) void emit_kernel(const float* __restrict__ pred,
                                                   const int* __restrict__ target,
                                                   float* __restrict__ emA,
                                                   float* __restrict__ emB,
                                                   int T, int V, int L) {
    int wave = threadIdx.x >> 6;
    int lane = threadIdx.x & 63;
    int row = blockIdx.x * 4 + wave;            // row = b*T + t
    const float* rowp = pred + (size_t)row * V;
    int nq = V >> 2;                            // 250 float4s
    float4 v0, v1, v2, v3;
    const float4 fill = make_float4(-3.0e38f, -3.0e38f, -3.0e38f, -3.0e38f);
    v0 = (lane       < nq) ? ((const float4*)rowp)[lane]       : fill;
    v1 = (lane + 64  < nq) ? ((const float4*)rowp)[lane + 64]  : fill;
    v2 = (lane + 128 < nq) ? ((const float4*)rowp)[lane + 128] : fill;
    v3 = (lane + 192 < nq) ? ((const float4*)rowp)[lane + 192] : fill;
    float lm = fmaxf(fmaxf(fmaxf(v0.x, v0.y), fmaxf(v0.z, v0.w)),
               fmaxf(fmaxf(fmaxf(v1.x, v1.y), fmaxf(v1.z, v1.w)),
               fmaxf(fmaxf(fmaxf(v2.x, v2.y), fmaxf(v2.z, v2.w)),
                     fmaxf(fmaxf(v3.x, v3.y), fmaxf(v3.z, v3.w)))));
    #pragma unroll
    for (int off = 32; off > 0; off >>= 1) lm = fmaxf(lm, __shfl_xor(lm, off));
    float mm = lm * LOG2E;                      // row max in log2 units
    float ls = 0.f;
    if (lane < nq)
        ls += x2(fmaf(v0.x, LOG2E, -mm)) + x2(fmaf(v0.y, LOG2E, -mm))
            + x2(fmaf(v0.z, LOG2E, -mm)) + x2(fmaf(v0.w, LOG2E, -mm));
    if (lane + 64 < nq)
        ls += x2(fmaf(v1.x, LOG2E, -mm)) + x2(fmaf(v1.y, LOG2E, -mm))
            + x2(fmaf(v1.z, LOG2E, -mm)) + x2(fmaf(v1.w, LOG2E, -mm));
    if (lane + 128 < nq)
        ls += x2(fmaf(v2.x, LOG2E, -mm)) + x2(fmaf(v2.y, LOG2E, -mm))
            + x2(fmaf(v2.z, LOG2E, -mm)) + x2(fmaf(v2.w, LOG2E, -mm));
    if (lane + 192 < nq)
        ls += x2(fmaf(v3.x, LOG2E, -mm)) + x2(fmaf(v3.y, LOG2E, -mm))
            + x2(fmaf(v3.z, LOG2E, -mm)) + x2(fmaf(v3.w, LOG2E, -mm));
    #pragma unroll
    for (int off = 32; off > 0; off >>= 1) ls += __shfl_xor(ls, off);
    float n2 = mm + lg2(ls);                    // log2 normalizer

    int b = row / T;
    int t = row - b * T;
    int p = t >> 1, par = t & 1;
    const int* tg = target + b * L;
    float* arow = emA + ((size_t)b * (T >> 1) + p) * 256;
    for (int j = lane; j < L; j += 64) {
        int tok = tg[j];
        arow[(j >> 1) * 4 + par * 2 + (j & 1)] = x2(fmaf(rowp[tok], LOG2E, -n2));
    }
    float blank_logit = __shfl(v0.x, 0);        // pred[row][0] (token 0)
    emB[((size_t)b * (T >> 1) + p) * 128 + lane * 2 + par] =
        x2(fmaf(blank_logit, LOG2E, -n2));
}

// One linear-domain DP state update (no load). stored = true * 2^K per lane;
// left-neighbor value re-framed by ldexp(K-Kp); neighbor pre-selects what
// this lane needs (skipAn) -> 2 bpermutes. Zero transcendentals.
#define STEP_CORE(EX0, EX1, EB)                                           \
  do {                                                                    \
    float r  = a3 + a2;                                                   \
    float q  = a1 + a0;                                                   \
    float w  = skipAn ? r : a3;     /* value my RIGHT neighbor needs */   \
    float ur = __shfl_up(w, 1);                                           \
    int   Kp = __shfl_up(K, 1);                                           \
    K = act ? K : Kp;                                                     \
    float uc = ldexpf(ur, K - Kp);                                        \
    float sb = s1 + star_st;                                              \
    if (lane == 0) uc = sb;                                               \
    S += slot0 ? q : r;                                                   \
    a2 = (EX1) * (a2 + (skipB ? q : a1));                                 \
    a0 = (EX0) * (a0 + uc);                                               \
    a1 = (EB) * q;                                                        \
    a3 = (EB) * r;                                                        \
    s1 = (EB) * sb;                                                       \
    act = act || (uc > 0.0f);                                             \
  } while (0)

// One PAIR step: consume prefetched float4/float2 (2 timesteps), reload them
// 8 pairs (16 steps) ahead. Named regs only — no alloca -> no LDS promotion.
#define DP_STEP2(PA, PB)                                                  \
  do {                                                                    \
    float4 e4 = PA; float2 b2 = PB;                                       \
    int pp = p + 8; if (pp > NPm1) pp = NPm1;                             \
    PA = eAb[(size_t)pp * 64 + lane];                                     \
    PB = eBb[(size_t)pp * 64 + lane];                                     \
    STEP_CORE(e4.x, e4.y, b2.x);                                          \
    STEP_CORE(e4.z, e4.w, b2.y);                                          \
    ++p;                                                                  \
  } while (0)

// Per-lane renorm: rescale stored values so lane max ~ 1, fold into K.
// Inactive lanes (m4==0) keep K (adoption handles them). S shares the frame.
#define RENORM                                                            \
  do {                                                                    \
    float m4 = fmaxf(fmaxf(a0, a1), fmaxf(a2, a3));                       \
    int e = (int)((__float_as_uint(m4) >> 23) & 255u) - 127;              \
    int d = act ? -e : 0;                                                 \
    float sc = ldexpf(1.0f, d);                                           \
    a0 *= sc; a1 *= sc; a2 *= sc; a3 *= sc; s1 *= sc; S *= sc;            \
    K += d;                                                               \
    star_st = ldexpf(sbase, K);                                           \
  } while (0)

// Phase 2: barrier-free single-wave W-CTC DP, LINEAR domain with per-lane
// block exponents. Lane i owns states s=4i+2..4i+5; star (true value 1) and
// s=1 live on lane 0. total = sum over t of (alpha_t[ll] + alpha_t[lb]).
// __launch_bounds__(64,1): only 32 waves exist chip-wide — lift the VGPR
// budget so the 8x(float4+float2) prefetch pipeline STAYS IN REGISTERS
// (R6's VGPR=32 showed the allocator sank the prefetch loads to their uses,
// exposing ~300 cyc of cache latency per step).
__global__ __launch_bounds__(64, 1) void dp_kernel(const float* __restrict__ emA,
                                                   const float* __restrict__ emB,
                                                   const int* __restrict__ target,
                                                   const int* __restrict__ tlen,
                                                   float* __restrict__ nll,
                                                   int T, int L) {
    int b = blockIdx.x;
    int lane = threadIdx.x;
    const float4* eAb = (const float4*)(emA + (size_t)b * (T >> 1) * 256);
    const float2* eBb = (const float2*)(emB + (size_t)b * (T >> 1) * 128);
    const int* tg = target + b * L;
    int NPm1 = (T >> 1) - 1;

    // pair 0 (t=0 init + t=1 step) loads first
    float4 p0 = eAb[lane];
    float2 q0 = eBb[lane];

    // 8 named prefetch register sets, pairs 1..8 (16 timesteps of cover)
    float4 A0, A1, A2, A3, A4, A5, A6, A7;
    float2 B0, B1, B2, B3, B4, B5, B6, B7;
    #define PRELOAD(KK)                                                    \
      { int pp = 1 + KK; if (pp > NPm1) pp = NPm1;                         \
        A##KK = eAb[(size_t)pp * 64 + lane];                               \
        B##KK = eBb[(size_t)pp * 64 + lane]; }
    PRELOAD(0) PRELOAD(1) PRELOAD(2) PRELOAD(3)
    PRELOAD(4) PRELOAD(5) PRELOAD(6) PRELOAD(7)
    #undef PRELOAD

    int t0 = tg[2 * lane];
    int t1 = tg[2 * lane + 1];
    int tprev = __shfl_up(t1, 1);                // garbage on lane 0 (unused)
    bool skipA = (lane == 0) || (t0 != tprev);
    // my right neighbor's skipA (what to pre-select for them); lane63 dontcare
    bool skipAn = (__shfl_down((int)skipA, 1) != 0);
    bool skipB = (t1 != t0);

    int tl = tlen[b];
    int ll = 2 * tl;
    int lane_e = (ll - 2) >> 2;
    bool slot0 = ((ll - 2) & 3) == 0;            // ll,lb in (a0,a1) vs (a2,a3)

    // t=0 init (linear): star=1 (lane0), s=1 -> blank prob, s=2 -> label0 prob
    float a0 = (lane == 0) ? p0.x : 0.f;
    float a1 = 0.f, a2 = 0.f, a3 = 0.f;
    float s1 = (lane == 0) ? q0.x : 0.f;
    float sbase = (lane == 0) ? 1.0f : 0.0f;
    int   K = 0;
    float star_st = sbase;                       // star stored = 1 * 2^K (lane 0)
    bool  act = (lane == 0);
    float S = 0.f;                               // running sum of alpha_t[ll]+[lb]

    // step t=1 from pair 0, parity 1
    STEP_CORE(p0.z, p0.w, q0.y);

    // pairs 1..NPm1 (each = 2 timesteps), renorm every 2 pairs (4 steps)
    int p = 1;
    int ng = NPm1 >> 3;                          // full groups of 8 pairs
    for (int g = 0; g < ng; ++g) {
        DP_STEP2(A0, B0); DP_STEP2(A1, B1); RENORM;
        DP_STEP2(A2, B2); DP_STEP2(A3, B3); RENORM;
        DP_STEP2(A4, B4); DP_STEP2(A5, B5); RENORM;
        DP_STEP2(A6, B6); DP_STEP2(A7, B7); RENORM;
    }
    // tail (< 8 pairs): regs already hold pairs p..NPm1 (clamped preloads)
    if (p <= NPm1) { DP_STEP2(A0, B0); }
    if (p <= NPm1) { DP_STEP2(A1, B1); RENORM; }
    if (p <= NPm1) { DP_STEP2(A2, B2); }
    if (p <= NPm1) { DP_STEP2(A3, B3); RENORM; }
    if (p <= NPm1) { DP_STEP2(A4, B4); }
    if (p <= NPm1) { DP_STEP2(A5, B5); RENORM; }
    if (p <= NPm1) { DP_STEP2(A6, B6); }

    {   // final alpha_{T-1}[ll],[lb] contribution
        float q = a1 + a0;
        float r = a3 + a2;
        S += slot0 ? q : r;
    }
    float Sv = __shfl(S, lane_e);
    int   Kv = __shfl(K, lane_e);
    if (lane == 0) nll[b] = -((lg2(Sv) - (float)Kv) * LN2);   // back to nats
}

// Phase 3: out = mean_b( nll[b] / tlen[b] )
__global__ __launch_bounds__(64) void fin_kernel(const float* __restrict__ nll,
                                                 const int* __restrict__ tlen,
                                                 float* __restrict__ out, int B) {
    int tid = threadIdx.x;
    float v = (tid < B) ? nll[tid] / (float)tlen[tid] : 0.f;
    #pragma unroll
    for (int off = 32; off > 0; off >>= 1) v += __shfl_xor(v, off);
    if (tid == 0) out[0] = v / (float)B;
}

extern "C" void kernel_launch(void* const* d_in, const int* in_sizes, int n_in,
                              void* d_out, int out_size, void* d_ws, size_t ws_size,
                              hipStream_t stream) {
    const float* pred   = (const float*)d_in[0];
    const int*   target = (const int*)d_in[1];
    const int*   tlen   = (const int*)d_in[2];
    int B = in_sizes[2];
    int L = in_sizes[1] / B;            // 128
    int V = 1000;                       // fixed by the problem
    int T = in_sizes[0] / (B * V);      // 1024

    float* ws  = (float*)d_ws;
    float* nll = ws;                    // 64 floats
    float* emB = ws + 64;               // B*(T/2)*128 floats (~8.4 MB)
    float* emA = emB + (size_t)B * (T >> 1) * 128;  // B*(T/2)*256 (~16.8 MB)

    emit_kernel<<<(B * T) / 4, 256, 0, stream>>>(pred, target, emA, emB, T, V, L);
    dp_kernel<<<B, 64, 0, stream>>>(emA, emB, target, tlen, nll, T, L);
    fin_kernel<<<1, 64, 0, stream>>>(nll, tlen, (float*)d_out, B);
}

// Round 8
// 310.656 us; speedup vs baseline: 1.0955x; 1.0218x over previous
//
#include <hip/hip_runtime.h>

#define LOG2E 1.4426950408889634f
#define LN2   0.6931471805599453f

__device__ __forceinline__ float x2(float x)  { return __builtin_amdgcn_exp2f(x); }
__device__ __forceinline__ float lg2(float x) { return __builtin_amdgcn_logf(x); }

// async global->LDS DMA (wave-uniform base, lane*size scatter)
#define GLLDS(g, l, sz)                                                    \
    __builtin_amdgcn_global_load_lds(                                      \
        (const __attribute__((address_space(1))) void*)(g),                \
        (__attribute__((address_space(3))) void*)(l), (sz), 0, 0)

// Phase 1: per-(b,t) softmax normalizer + gather token PROBABILITIES into
// pair-major emA (float4/lane: labels 2i,2i+1 at par0 then par1) and a
// compact blank stream emB[b*T + t]. One wave per row, no LDS, no barriers.
__global__ __launch_bounds__(256) void emit_kernel(const float* __restrict__ pred,
                                                   const int* __restrict__ target,
                                                   float* __restrict__ emA,
                                                   float* __restrict__ emB,
                                                   int T, int V, int L) {
    int wave = threadIdx.x >> 6;
    int lane = threadIdx.x & 63;
    int row = blockIdx.x * 4 + wave;            // row = b*T + t
    const float* rowp = pred + (size_t)row * V;
    int nq = V >> 2;                            // 250 float4s
    float4 v0, v1, v2, v3;
    const float4 fill = make_float4(-3.0e38f, -3.0e38f, -3.0e38f, -3.0e38f);
    v0 = (lane       < nq) ? ((const float4*)rowp)[lane]       : fill;
    v1 = (lane + 64  < nq) ? ((const float4*)rowp)[lane + 64]  : fill;
    v2 = (lane + 128 < nq) ? ((const float4*)rowp)[lane + 128] : fill;
    v3 = (lane + 192 < nq) ? ((const float4*)rowp)[lane + 192] : fill;
    float lm = fmaxf(fmaxf(fmaxf(v0.x, v0.y), fmaxf(v0.z, v0.w)),
               fmaxf(fmaxf(fmaxf(v1.x, v1.y), fmaxf(v1.z, v1.w)),
               fmaxf(fmaxf(fmaxf(v2.x, v2.y), fmaxf(v2.z, v2.w)),
                     fmaxf(fmaxf(v3.x, v3.y), fmaxf(v3.z, v3.w)))));
    #pragma unroll
    for (int off = 32; off > 0; off >>= 1) lm = fmaxf(lm, __shfl_xor(lm, off));
    float mm = lm * LOG2E;                      // row max in log2 units
    float ls = 0.f;
    if (lane < nq)
        ls += x2(fmaf(v0.x, LOG2E, -mm)) + x2(fmaf(v0.y, LOG2E, -mm))
            + x2(fmaf(v0.z, LOG2E, -mm)) + x2(fmaf(v0.w, LOG2E, -mm));
    if (lane + 64 < nq)
        ls += x2(fmaf(v1.x, LOG2E, -mm)) + x2(fmaf(v1.y, LOG2E, -mm))
            + x2(fmaf(v1.z, LOG2E, -mm)) + x2(fmaf(v1.w, LOG2E, -mm));
    if (lane + 128 < nq)
        ls += x2(fmaf(v2.x, LOG2E, -mm)) + x2(fmaf(v2.y, LOG2E, -mm))
            + x2(fmaf(v2.z, LOG2E, -mm)) + x2(fmaf(v2.w, LOG2E, -mm));
    if (lane + 192 < nq)
        ls += x2(fmaf(v3.x, LOG2E, -mm)) + x2(fmaf(v3.y, LOG2E, -mm))
            + x2(fmaf(v3.z, LOG2E, -mm)) + x2(fmaf(v3.w, LOG2E, -mm));
    #pragma unroll
    for (int off = 32; off > 0; off >>= 1) ls += __shfl_xor(ls, off);
    float n2 = mm + lg2(ls);                    // log2 normalizer

    int b = row / T;
    int t = row - b * T;
    int p = t >> 1, par = t & 1;
    const int* tg = target + b * L;
    float* arow = emA + ((size_t)b * (T >> 1) + p) * 256;
    for (int j = lane; j < L; j += 64) {
        int tok = tg[j];
        arow[(j >> 1) * 4 + par * 2 + (j & 1)] = x2(fmaf(rowp[tok], LOG2E, -n2));
    }
    float blank_logit = __shfl(v0.x, 0);        // pred[row][0] (token 0)
    if (lane == 0) emB[row] = x2(fmaf(blank_logit, LOG2E, -n2));
}

// One linear-domain DP state update. stored = true * 2^K per lane;
// left-neighbor value re-framed by ldexp(K-Kp); neighbor pre-selects what
// this lane needs (skipAn) -> 2 bpermutes. Zero transcendentals.
#define STEP_CORE(EX0, EX1, EB)                                           \
  do {                                                                    \
    float r  = a3 + a2;                                                   \
    float q  = a1 + a0;                                                   \
    float w  = skipAn ? r : a3;     /* value my RIGHT neighbor needs */   \
    float ur = __shfl_up(w, 1);                                           \
    int   Kp = __shfl_up(K, 1);                                           \
    K = act ? K : Kp;                                                     \
    float uc = ldexpf(ur, K - Kp);                                        \
    float sb = s1 + star_st;                                              \
    if (lane == 0) uc = sb;                                               \
    S += slot0 ? q : r;                                                   \
    a2 = (EX1) * (a2 + (skipB ? q : a1));                                 \
    a0 = (EX0) * (a0 + uc);                                               \
    a1 = (EB) * q;                                                        \
    a3 = (EB) * r;                                                        \
    s1 = (EB) * sb;                                                       \
    act = act || (uc > 0.0f);                                             \
  } while (0)

// Per-lane renorm: rescale stored values so lane max ~ 1, fold into K.
#define RENORM                                                            \
  do {                                                                    \
    float m4 = fmaxf(fmaxf(a0, a1), fmaxf(a2, a3));                       \
    int e = (int)((__float_as_uint(m4) >> 23) & 255u) - 127;              \
    int d = act ? -e : 0;                                                 \
    float sc = ldexpf(1.0f, d);                                           \
    a0 *= sc; a1 *= sc; a2 *= sc; a3 *= sc; s1 *= sc; S *= sc;            \
    K += d;                                                               \
    star_st = ldexpf(sbase, K);                                           \
  } while (0)

#define BATCH 24   // pairs per LDS staging batch (48 timesteps of cover)

// Phase 2: barrier-free single-wave W-CTC DP, LINEAR domain with per-lane
// block exponents. Emissions staged global->LDS via global_load_lds in
// double-buffered batches of 24 pairs; one s_waitcnt vmcnt(0) per batch
// (issued a full superstep earlier -> no stall). This sidesteps R6/R7's
// register-allocator load-sinking: the DMA queue, not VGPRs, holds the
// in-flight data.
__global__ __launch_bounds__(64, 1) void dp_kernel(const float* __restrict__ emA,
                                                   const float* __restrict__ emB,
                                                   const int* __restrict__ target,
                                                   const int* __restrict__ tlen,
                                                   float* __restrict__ nll,
                                                   int T, int L) {
    __shared__ float4 sA[2][BATCH][64];   // 49152 B
    __shared__ float  sB[2][64];          // 512 B (blank row, 64-f padded)

    int b = blockIdx.x;
    int lane = threadIdx.x;
    int NP = T >> 1;
    int NPm1 = NP - 1;
    const float* eAb = emA + (size_t)b * NP * 256;
    const float* eBb = emB + (size_t)b * T;
    const int* tg = target + b * L;

    int NPc = NP - 1;                     // pairs 1..NP-1 are staged
    int NB = (NPc + BATCH - 1) / BATCH;

    // issue one batch of BATCH pair-rows (+1 blank row) into LDS buf
    #define ISSUE(c, buf)                                                  \
      do {                                                                 \
        int base_ = 1 + BATCH * (c);                                       \
        _Pragma("unroll")                                                  \
        for (int j_ = 0; j_ < BATCH; ++j_) {                               \
            int pr_ = base_ + j_; if (pr_ > NPm1) pr_ = NPm1;              \
            GLLDS(eAb + (size_t)pr_ * 256, &sA[buf][j_][0], 16);           \
        }                                                                  \
        GLLDS(eBb + base_ * 2, &sB[buf][0], 4);                            \
      } while (0)

    ISSUE(0, 0);
    if (NB > 1) ISSUE(1, 1);

    // pair 0 (t=0 init + t=1 step): direct scalar loads, outside the loop
    float4 p0 = ((const float4*)eAb)[lane];
    float be0 = eBb[0], be1 = eBb[1];

    int t0 = tg[2 * lane];
    int t1 = tg[2 * lane + 1];
    int tprev = __shfl_up(t1, 1);                // garbage on lane 0 (unused)
    bool skipA = (lane == 0) || (t0 != tprev);
    bool skipAn = (__shfl_down((int)skipA, 1) != 0);  // right neighbor's skipA
    bool skipB = (t1 != t0);

    int tl = tlen[b];
    int ll = 2 * tl;
    int lane_e = (ll - 2) >> 2;
    bool slot0 = ((ll - 2) & 3) == 0;            // ll,lb in (a0,a1) vs (a2,a3)

    // t=0 init (linear): star=1 (lane0), s=1 -> blank prob, s=2 -> label0 prob
    float a0 = (lane == 0) ? p0.x : 0.f;
    float a1 = 0.f, a2 = 0.f, a3 = 0.f;
    float s1 = (lane == 0) ? be0 : 0.f;
    float sbase = (lane == 0) ? 1.0f : 0.0f;
    int   K = 0;
    float star_st = sbase;                       // star stored = 1 * 2^K (lane 0)
    bool  act = (lane == 0);
    float S = 0.f;                               // running sum of alpha_t[ll]+[lb]

    // step t=1 from pair 0, parity 1
    STEP_CORE(p0.z, p0.w, be1);

    for (int c = 0; c < NB; ++c) {
        asm volatile("s_waitcnt vmcnt(0)" ::: "memory");  // batch c resident
        int buf = c & 1;
        int jn = NPc - BATCH * c; if (jn > BATCH) jn = BATCH;
        // consume BATCH pairs with a 1-pair register rotate (covers ds latency)
        float4 e4 = sA[buf][0][lane];
        float2 b2 = *(const float2*)&sB[buf][0];
        for (int j = 0; j < jn; ++j) {
            int j1 = j + 1; if (j1 >= BATCH) j1 = 0;
            float4 e4n = sA[buf][j1][lane];
            float2 b2n = *(const float2*)&sB[buf][2 * j1];
            STEP_CORE(e4.x, e4.y, b2.x);
            STEP_CORE(e4.z, e4.w, b2.y);
            if (j & 1) RENORM;
            e4 = e4n; b2 = b2n;
        }
        if (c + 2 < NB) ISSUE(c + 2, buf);       // refill the buf just drained
    }
    #undef ISSUE

    {   // final alpha_{T-1}[ll],[lb] contribution
        float q = a1 + a0;
        float r = a3 + a2;
        S += slot0 ? q : r;
    }
    float Sv = __shfl(S, lane_e);
    int   Kv = __shfl(K, lane_e);
    if (lane == 0) nll[b] = -((lg2(Sv) - (float)Kv) * LN2);   // back to nats
}

// Phase 3: out = mean_b( nll[b] / tlen[b] )
__global__ __launch_bounds__(64) void fin_kernel(const float* __restrict__ nll,
                                                 const int* __restrict__ tlen,
                                                 float* __restrict__ out, int B) {
    int tid = threadIdx.x;
    float v = (tid < B) ? nll[tid] / (float)tlen[tid] : 0.f;
    #pragma unroll
    for (int off = 32; off > 0; off >>= 1) v += __shfl_xor(v, off);
    if (tid == 0) out[0] = v / (float)B;
}

extern "C" void kernel_launch(void* const* d_in, const int* in_sizes, int n_in,
                              void* d_out, int out_size, void* d_ws, size_t ws_size,
                              hipStream_t stream) {
    const float* pred   = (const float*)d_in[0];
    const int*   target = (const int*)d_in[1];
    const int*   tlen   = (const int*)d_in[2];
    int B = in_sizes[2];
    int L = in_sizes[1] / B;            // 128
    int V = 1000;                       // fixed by the problem
    int T = in_sizes[0] / (B * V);      // 1024

    float* ws  = (float*)d_ws;
    float* nll = ws;                    // 64 floats
    float* emB = ws + 64;               // B*T floats (blank probs, compact)
    float* emA = emB + (size_t)B * T;   // B*(T/2)*256 floats (~16.8 MB)
                                        // (emB precedes emA so the blank
                                        // batch-load's 64-lane over-read on
                                        // the last batch stays inside ws)

    emit_kernel<<<(B * T) / 4, 256, 0, stream>>>(pred, target, emA, emB, T, V, L);
    dp_kernel<<<B, 64, 0, stream>>>(emA, emB, target, tlen, nll, T, L);
    fin_kernel<<<1, 64, 0, stream>>>(nll, tlen, (float*)d_out, B);
}